// Round 6
// baseline (1163.231 us; speedup 1.0000x reference)
//
#include <hip/hip_runtime.h>
#include <hip/hip_bf16.h>
#include <stdint.h>

#define T_STEPS 256
#define BATCH   64
#define IN_DIM  512
#define HID     1024
#define OUT_DIM 256
#define G4      4096
#define SENT32  0x7FC07FC0u
#define SENT64  0x7FC07FC07FC07FC0ULL
#define WSTRIDE 1028   // 1024 + 4: rows offset by 4 banks -> full 32-bank engagement

__device__ __forceinline__ float bfbits2f(uint32_t b16) {
    return __uint_as_float(b16 << 16);
}
__device__ __forceinline__ uint32_t f2bfbits(float f) {
    uint32_t u = __float_as_uint(f);
    u += 0x7fffu + ((u >> 16) & 1u);   // RNE; finite inputs, never 0x7FC0
    return u >> 16;
}
__device__ __forceinline__ float fast_sigmoid(float x) {
    return 1.f / (1.f + __expf(-x));
}
__device__ __forceinline__ float fast_tanh(float x) {
    return 2.f / (1.f + __expf(-2.f * x)) - 1.f;
}
__device__ __forceinline__ bool any_sent(uint64_t v) {
    uint64_t x = v ^ SENT64;
    return (((x - 0x0001000100010001ULL) & ~x) & 0x8000800080008000ULL) != 0ULL;
}
__device__ __forceinline__ uint64_t poll_load(const uint64_t* p) {
    return __hip_atomic_load(p, __ATOMIC_RELAXED, __HIP_MEMORY_SCOPE_AGENT);
}

// ---------------------------------------------------------------- init
__global__ void init_sent(uint32_t* __restrict__ p, int n) {
    int i = blockIdx.x * 256 + threadIdx.x;
    if (i < n) p[i] = SENT32;
}

// ---------------------------------------------------------------- GEMM C[M][N] = A[M][K]*B[N][K]^T + bias (fc only)
template<bool ABF16>
__global__ __launch_bounds__(256) void gemm_bt(
    const void* __restrict__ Av, long lda,
    const float* __restrict__ Bw, int ldb,
    const float* __restrict__ bias1,
    float* __restrict__ C, int ldc, int K)
{
    __shared__ float a_lds[64][68];
    __shared__ float w_lds[64][65];
    const int tid = threadIdx.x;
    const int m0 = blockIdx.y * 64, n0 = blockIdx.x * 64;
    const int kl = tid & 63, grp = tid >> 6;
    const int cc = tid & 31, r0 = (tid >> 5) * 8;

    float acc[16];
#pragma unroll
    for (int i = 0; i < 16; ++i) acc[i] = 0.f;

    for (int k0 = 0; k0 < K; k0 += 64) {
        __syncthreads();
#pragma unroll
        for (int i = 0; i < 16; ++i) {
            int r = grp + 4 * i;
            long ai = (long)(m0 + r) * lda + k0 + kl;
            float av = ABF16 ? bfbits2f(((const uint16_t*)Av)[ai])
                             : ((const float*)Av)[ai];
            a_lds[kl][r] = av;
            w_lds[kl][r] = Bw[(long)(n0 + r) * ldb + k0 + kl];
        }
        __syncthreads();
#pragma unroll 16
        for (int k = 0; k < 64; ++k) {
            float4 A0 = *(const float4*)&a_lds[k][r0];
            float4 A1 = *(const float4*)&a_lds[k][r0 + 4];
            float w0 = w_lds[k][cc], w1 = w_lds[k][cc + 32];
            float a[8] = {A0.x, A0.y, A0.z, A0.w, A1.x, A1.y, A1.z, A1.w};
#pragma unroll
            for (int i = 0; i < 8; ++i) {
                acc[i]     += a[i] * w0;
                acc[8 + i] += a[i] * w1;
            }
        }
    }
    float b0 = bias1[n0 + cc], b1 = bias1[n0 + cc + 32];
#pragma unroll
    for (int i = 0; i < 8; ++i) {
        C[(long)(m0 + r0 + i) * ldc + n0 + cc]      = acc[i]     + b0;
        C[(long)(m0 + r0 + i) * ldc + n0 + cc + 32] = acc[8 + i] + b1;
    }
}

// ---------------------------------------------------------------- fused xz + LSTM recurrence (batch 63)
// 256 blocks x 256 threads, 1 block/CU (90.5 KB LDS). Block g owns units
// [4g,4g+4) -> 16 gate rows. W_hh slice lives in LDS (on-chip residency is
// architectural -- r1..r5 all lost the weights to scratch spills/remat).
// Row stride 1028 + kpart-rotated iteration order -> all 32 banks engaged.
// Per step: 256 threads poll one u64 granule each (3-deep pipelined), stage
// to LDS, barrier, 16x(W,h) b128 LDS reads + 64 fma, 16-lane reduce, z_lds,
// barrier, gates on threads 0..3, pack, ONE u64 agent store.
#define GROWX(RR) ((long)((RR) >> 2) * HID + 4 * g + ((RR) & 3))

__global__ __launch_bounds__(256, 1) void lstm_rec(
    const float* __restrict__ W_hh,   // [4096][1024]
    const float* __restrict__ x,      // [256][64][512]
    const float* __restrict__ W_ih,   // [4096][512]
    const float* __restrict__ b_ih,
    const float* __restrict__ b_hh,
    uint64_t* __restrict__ h_all)     // [256][256] u64 (= [256][1024] bf16)
{
    __shared__ float W_lds[16][WSTRIDE];       // 65.8 KB
    __shared__ float h_lds[2][HID];            //  8   KB
    __shared__ float xz_lds[16][T_STEPS + 1];  // 16.4 KB
    __shared__ float z_lds[16];

    const int g   = blockIdx.x;   // 0..255
    const int tid = threadIdx.x;
    const int kpart = tid & 15;
    const int row   = tid >> 4;        // 0..15: gate = row>>2, ju = row&3
    const long grow = GROWX(row);

    // ---------------- W_hh slice -> LDS (once). Thread owns its own stripe.
    {
        const float* wsrc = W_hh + grow * HID;
#pragma unroll
        for (int i = 0; i < 16; ++i) {
            const int col = kpart * 64 + ((i + kpart) & 15) * 4;
            *(float4*)&W_lds[row][col] = *(const float4*)(wsrc + col);
        }
    }

    // ---------------- prologue: xz rows for this block (into LDS)
    {
        const int wv = tid >> 6;        // wave 0..3 -> rows 4wv..4wv+3
        const int ln = tid & 63;        // k-part: x cols [8ln, 8ln+8)
        const int rr0 = 4 * wv;
        const long gr0 = GROWX(rr0), gr1 = GROWX(rr0 + 1),
                   gr2 = GROWX(rr0 + 2), gr3 = GROWX(rr0 + 3);
        const float4 p0a = *(const float4*)(W_ih + gr0 * IN_DIM + 8 * ln);
        const float4 p0b = *(const float4*)(W_ih + gr0 * IN_DIM + 8 * ln + 4);
        const float4 p1a = *(const float4*)(W_ih + gr1 * IN_DIM + 8 * ln);
        const float4 p1b = *(const float4*)(W_ih + gr1 * IN_DIM + 8 * ln + 4);
        const float4 p2a = *(const float4*)(W_ih + gr2 * IN_DIM + 8 * ln);
        const float4 p2b = *(const float4*)(W_ih + gr2 * IN_DIM + 8 * ln + 4);
        const float4 p3a = *(const float4*)(W_ih + gr3 * IN_DIM + 8 * ln);
        const float4 p3b = *(const float4*)(W_ih + gr3 * IN_DIM + 8 * ln + 4);
        const float bs0 = b_ih[gr0] + b_hh[gr0];
        const float bs1 = b_ih[gr1] + b_hh[gr1];
        const float bs2 = b_ih[gr2] + b_hh[gr2];
        const float bs3 = b_ih[gr3] + b_hh[gr3];
        for (int t = 0; t < T_STEPS; ++t) {
            const float* xp = x + ((long)t * BATCH + 63) * IN_DIM + 8 * ln;
            const float4 xa = *(const float4*)xp;
            const float4 xb = *(const float4*)(xp + 4);
            float s0 = xa.x*p0a.x + xa.y*p0a.y + xa.z*p0a.z + xa.w*p0a.w
                     + xb.x*p0b.x + xb.y*p0b.y + xb.z*p0b.z + xb.w*p0b.w;
            float s1 = xa.x*p1a.x + xa.y*p1a.y + xa.z*p1a.z + xa.w*p1a.w
                     + xb.x*p1b.x + xb.y*p1b.y + xb.z*p1b.z + xb.w*p1b.w;
            float s2 = xa.x*p2a.x + xa.y*p2a.y + xa.z*p2a.z + xa.w*p2a.w
                     + xb.x*p2b.x + xb.y*p2b.y + xb.z*p2b.z + xb.w*p2b.w;
            float s3 = xa.x*p3a.x + xa.y*p3a.y + xa.z*p3a.z + xa.w*p3a.w
                     + xb.x*p3b.x + xb.y*p3b.y + xb.z*p3b.z + xb.w*p3b.w;
#pragma unroll
            for (int d = 1; d < 64; d <<= 1) {
                s0 += __shfl_xor(s0, d, 64);
                s1 += __shfl_xor(s1, d, 64);
                s2 += __shfl_xor(s2, d, 64);
                s3 += __shfl_xor(s3, d, 64);
            }
            if (ln == 0) {
                xz_lds[rr0 + 0][t] = s0 + bs0;
                xz_lds[rr0 + 1][t] = s1 + bs1;
                xz_lds[rr0 + 2][t] = s2 + bs2;
                xz_lds[rr0 + 3][t] = s3 + bs3;
            }
        }
    }

    // zero h_0 into buffer 0
    {
        float4 z4 = {0.f, 0.f, 0.f, 0.f};
        *(float4*)&h_lds[0][4 * tid] = z4;
    }
    __syncthreads();   // W_lds + xz_lds + h_lds[0] ready

    float c_state = 0.f;                 // used by threads 0..3 (unit = tid)
    float xz_next = xz_lds[row][0];

    for (int t = 0; t < T_STEPS; ++t) {
        float* hb = h_lds[t & 1];
        if (t > 0) {
            const uint64_t* src = h_all + (size_t)(t - 1) * 256 + tid;
            // 3-deep rotating pipelined poll on one u64 granule
            uint64_t v  = poll_load(src);
            uint64_t a_ = poll_load(src);
            uint64_t b_ = poll_load(src);
            while (any_sent(v)) {
                v = a_; a_ = b_; b_ = poll_load(src);
            }
            float4 f0 = { bfbits2f((uint32_t)( v        & 0xFFFFu)),
                          bfbits2f((uint32_t)((v >> 16) & 0xFFFFu)),
                          bfbits2f((uint32_t)((v >> 32) & 0xFFFFu)),
                          bfbits2f((uint32_t)((v >> 48) & 0xFFFFu)) };
            *(float4*)&hb[4 * tid] = f0;
        }
        __syncthreads();   // A: h ready
        asm volatile("" ::: "memory");   // block LICM from hoisting W_lds reads

        const float xz_cur = xz_next;
        const int tn = (t + 1 < T_STEPS) ? t + 1 : t;
        xz_next = xz_lds[row][tn];       // LDS broadcast prefetch

        float a0 = 0.f, a1 = 0.f, a2 = 0.f, a3 = 0.f;
#pragma unroll
        for (int i = 0; i < 16; ++i) {
            const int col = kpart * 64 + ((i + kpart) & 15) * 4;
            const float4 wv4 = *(const float4*)&W_lds[row][col];
            const float4 hv  = *(const float4*)&hb[col];
            a0 = fmaf(wv4.x, hv.x, a0);
            a1 = fmaf(wv4.y, hv.y, a1);
            a2 = fmaf(wv4.z, hv.z, a2);
            a3 = fmaf(wv4.w, hv.w, a3);
        }
        float sum = (a0 + a1) + (a2 + a3);
        sum += __shfl_xor(sum, 1, 16);
        sum += __shfl_xor(sum, 2, 16);
        sum += __shfl_xor(sum, 4, 16);
        sum += __shfl_xor(sum, 8, 16);
        if (kpart == 0) z_lds[row] = sum + xz_cur;
        __syncthreads();   // B: z ready; h reads done

        // gates + state update + single u64 publish (threads 0..3, wave 0)
        if (tid < 4) {
            const float zi = z_lds[tid],     zf = z_lds[4 + tid];
            const float zg = z_lds[8 + tid], zo = z_lds[12 + tid];
            const float ii = fast_sigmoid(zi);
            const float ff = fast_sigmoid(zf);
            const float gg = fast_tanh(zg);
            const float oo = fast_sigmoid(zo);
            c_state = ff * c_state + ii * gg;
            const float h = oo * fast_tanh(c_state);
            uint32_t hbv = f2bfbits(h);
            uint32_t lo  = hbv | (__shfl_down(hbv, 1, 64) << 16);  // tid0: h0|h1, tid2: h2|h3
            uint64_t A   = (uint64_t)lo | ((uint64_t)__shfl(lo, 2, 64) << 32);
            if (tid == 0) {
                __hip_atomic_store(&h_all[(size_t)t * 256 + g], A,
                                   __ATOMIC_RELAXED, __HIP_MEMORY_SCOPE_AGENT);
            }
        }
    }
}

// ---------------------------------------------------------------- launch
extern "C" void kernel_launch(void* const* d_in, const int* in_sizes, int n_in,
                              void* d_out, int out_size, void* d_ws, size_t ws_size,
                              hipStream_t stream) {
    const float* x    = (const float*)d_in[0];
    const float* W_ih = (const float*)d_in[1];
    const float* W_hh = (const float*)d_in[2];
    const float* b_ih = (const float*)d_in[3];
    const float* b_hh = (const float*)d_in[4];
    const float* fc_W = (const float*)d_in[5];
    const float* fc_b = (const float*)d_in[6];
    float* out = (float*)d_out;

    uint64_t* h_all = (uint64_t*)d_ws;   // [256][256] u64 = 512 KB

    // re-sentinel every replay (graph-captured)
    init_sent<<<512, 256, 0, stream>>>((uint32_t*)h_all, T_STEPS * HID / 2);

    // fused xz-GEMM + sequential recurrence (1 block/CU, W_hh in LDS)
    lstm_rec<<<256, 256, 0, stream>>>(W_hh, x, W_ih, b_ih, b_hh, h_all);

    // out[t][o] = h_all[t][:]·fc_W[o][:] + fc_b[o]
    gemm_bt<true><<<dim3(OUT_DIM / 64, T_STEPS / 64), 256, 0, stream>>>(
        (const void*)h_all, HID, fc_W, HID, fc_b, out, OUT_DIM, HID);
}